// Round 3
// baseline (202.304 us; speedup 1.0000x reference)
//
#include <hip/hip_runtime.h>

#define S_DIM 4096
#define H_DIM 16
#define D_DIM 64
#define N_BLK 64          // S / 64 query blocks
#define PITCH 72          // bf16 elems per LDS row (64 + 8 pad)
#define NEG_INF_F (-1e30f)
#define QSCALE 0.125f     // 1/sqrt(64), exact

typedef __attribute__((ext_vector_type(4))) float f32x4;
typedef __attribute__((ext_vector_type(8))) short s16x8;
typedef __attribute__((ext_vector_type(4))) short s16x4;
typedef __attribute__((ext_vector_type(4))) unsigned int u32x4;
typedef __attribute__((ext_vector_type(2))) unsigned int u32x2;

__device__ __forceinline__ unsigned int fbits(float f) {
    return __builtin_bit_cast(unsigned int, f);
}
// pack two floats -> two bf16 (round-half-up; inputs never NaN here). lo=a, hi=b
__device__ __forceinline__ unsigned int pkbf(float a, float b) {
    return __builtin_amdgcn_perm(fbits(b) + 0x8000u, fbits(a) + 0x8000u, 0x07060302u);
}
__device__ __forceinline__ short f2bf1(float f) {
    return (short)((fbits(f) + 0x8000u) >> 16);
}

// Block = 4 waves x 32 queries = 2 query-blocks (n0, n0+1). Stages j = n0-2 .. n0+3.
// S^T trick: QK^T computed as K(A) x Q(B) -> lane holds S[query=l16][key=kt*16+4*quad+r];
// the lane's own exp'ed values form the PV A-fragment directly (key index permuted,
// V B-frags read with the same permutation) -- no cross-lane P movement.
// Pipelining: stage j+1's K/V rows prefetched into VGPRs while stage j computes;
// LDS tiles double-buffered -> ONE barrier per stage, global-load latency hidden.
__global__ __launch_bounds__(256, 4) void bsattn_kernel(
    const float* __restrict__ qg, const float* __restrict__ kg,
    const float* __restrict__ vg, float* __restrict__ outg)
{
    __shared__ short lds_k [2 * N_BLK * PITCH];   // K tiles bf16 [key][d], x2 buffers
    __shared__ short lds_vt[2 * D_DIM * PITCH];   // V^T tiles bf16 [d][key], x2 buffers

    const int tid  = threadIdx.x;
    const int w    = tid >> 6;
    const int lane = tid & 63;
    const int quad = lane >> 4;
    const int l16  = lane & 15;

    const int b  = blockIdx.z;
    const int h  = blockIdx.y;
    const int n0 = blockIdx.x << 1;
    const int n  = n0 + (w >> 1);                 // this wave's query block
    const int qrow0 = n * 64 + (w & 1) * 32;      // first of this wave's 32 queries

    // staging assignment: thread -> (key row tr, 16-float d-segment d0)
    const int tr = tid >> 2;
    const int d0 = (tid & 3) << 4;
    const size_t rowbase = ((size_t)(b * S_DIM + tr) * H_DIM + h) * D_DIM + d0;
    const size_t jstride = (size_t)64 * H_DIM * D_DIM;   // floats per key-block

    // ---- issue stage-0 prefetch FIRST (latency overlaps Q setup) ----
    float4 pkf[4], pvf[4];
    {
        const int jn = n0 - 2;
        if (jn >= 0) {                            // jn < N_BLK always here
            const float4* kp = reinterpret_cast<const float4*>(kg + rowbase + (size_t)jn * jstride);
            const float4* vp = reinterpret_cast<const float4*>(vg + rowbase + (size_t)jn * jstride);
            pkf[0] = kp[0]; pkf[1] = kp[1]; pkf[2] = kp[2]; pkf[3] = kp[3];
            pvf[0] = vp[0]; pvf[1] = vp[1]; pvf[2] = vp[2]; pvf[3] = vp[3];
        }
    }

    // ---- Q fragments (B-operand): bq[qt][half], pre-scaled, bf16 ----
    s16x8 bq[2][2];
#pragma unroll
    for (int qt = 0; qt < 2; ++qt) {
        const size_t qrow = ((size_t)(b * S_DIM + qrow0 + qt * 16 + l16) * H_DIM + h) * D_DIM;
#pragma unroll
        for (int hh = 0; hh < 2; ++hh) {
            const float4* qp = reinterpret_cast<const float4*>(qg + qrow + hh * 32 + quad * 8);
            float4 f0 = qp[0];
            float4 f1 = qp[1];
            u32x4 u;
            u.x = pkbf(f0.x * QSCALE, f0.y * QSCALE);
            u.y = pkbf(f0.z * QSCALE, f0.w * QSCALE);
            u.z = pkbf(f1.x * QSCALE, f1.y * QSCALE);
            u.w = pkbf(f1.z * QSCALE, f1.w * QSCALE);
            bq[qt][hh] = __builtin_bit_cast(s16x8, u);
        }
    }

    f32x4 o[2][4];                   // O accum [qt][dt], C layout (row=query, col=d)
    float m_run[2], l_run[2];
#pragma unroll
    for (int qt = 0; qt < 2; ++qt) {
        m_run[qt] = NEG_INF_F; l_run[qt] = 0.f;
#pragma unroll
        for (int dt = 0; dt < 4; ++dt) o[qt][dt] = (f32x4){0.f, 0.f, 0.f, 0.f};
    }

    for (int ji = 0; ji < 6; ++ji) {
        const int j = n0 - 2 + ji;                // key block index of this stage
        const int bo = (ji & 1) * (N_BLK * PITCH);
        short* const kbuf  = lds_k  + bo;
        short* const vtbuf = lds_vt + bo;

        // ---- pack prefetched regs -> LDS buffer (ji & 1) ----
        if (j >= 0 && j < N_BLK) {
            short* kd = kbuf + tr * PITCH + d0;
            u32x2 ka = {pkbf(pkf[0].x, pkf[0].y), pkbf(pkf[0].z, pkf[0].w)};
            u32x2 kb = {pkbf(pkf[1].x, pkf[1].y), pkbf(pkf[1].z, pkf[1].w)};
            u32x2 kc = {pkbf(pkf[2].x, pkf[2].y), pkbf(pkf[2].z, pkf[2].w)};
            u32x2 ke = {pkbf(pkf[3].x, pkf[3].y), pkbf(pkf[3].z, pkf[3].w)};
            *reinterpret_cast<u32x2*>(kd)      = ka;
            *reinterpret_cast<u32x2*>(kd + 4)  = kb;
            *reinterpret_cast<u32x2*>(kd + 8)  = kc;
            *reinterpret_cast<u32x2*>(kd + 12) = ke;
            float vf[16] = {pvf[0].x, pvf[0].y, pvf[0].z, pvf[0].w,
                            pvf[1].x, pvf[1].y, pvf[1].z, pvf[1].w,
                            pvf[2].x, pvf[2].y, pvf[2].z, pvf[2].w,
                            pvf[3].x, pvf[3].y, pvf[3].z, pvf[3].w};
#pragma unroll
            for (int i = 0; i < 16; ++i)
                vtbuf[(d0 + i) * PITCH + tr] = f2bf1(vf[i]);
        }
        __syncthreads();   // tile (ji&1) visible; all waves done with buffer (ji&1) from stage ji-2

        // ---- issue next stage's prefetch; vmcnt waits land at next iteration's pack ----
        if (ji < 5) {
            const int jn = j + 1;
            if (jn >= 0 && jn < N_BLK) {
                const float4* kp = reinterpret_cast<const float4*>(kg + rowbase + (size_t)jn * jstride);
                const float4* vp = reinterpret_cast<const float4*>(vg + rowbase + (size_t)jn * jstride);
                pkf[0] = kp[0]; pkf[1] = kp[1]; pkf[2] = kp[2]; pkf[3] = kp[3];
                pvf[0] = vp[0]; pvf[1] = vp[1]; pvf[2] = vp[2]; pvf[3] = vp[3];
            }
        }

        const int rel = j - n;
        if (j >= 0 && j < N_BLK && rel >= -2 && rel <= 2) {   // wave-uniform
            // ---- S^T = K x Q^T : sa[qt][kt], lane: query l16, keys kt*16+4*quad+r ----
            f32x4 sa[2][4];
#pragma unroll
            for (int kt = 0; kt < 4; ++kt) {
                const short* kbp = kbuf + (kt * 16 + l16) * PITCH + quad * 8;
                s16x8 kf0 = *reinterpret_cast<const s16x8*>(kbp);
                s16x8 kf1 = *reinterpret_cast<const s16x8*>(kbp + 32);
                f32x4 z = {0.f, 0.f, 0.f, 0.f};
                f32x4 a0 = __builtin_amdgcn_mfma_f32_16x16x32_bf16(kf0, bq[0][0], z, 0, 0, 0);
                sa[0][kt] = __builtin_amdgcn_mfma_f32_16x16x32_bf16(kf1, bq[0][1], a0, 0, 0, 0);
                f32x4 a1 = __builtin_amdgcn_mfma_f32_16x16x32_bf16(kf0, bq[1][0], z, 0, 0, 0);
                sa[1][kt] = __builtin_amdgcn_mfma_f32_16x16x32_bf16(kf1, bq[1][1], a1, 0, 0, 0);
            }

            // ---- online softmax per qt; P stays in registers ----
            s16x8 pa[2][2];
#pragma unroll
            for (int qt = 0; qt < 2; ++qt) {
                float mx = NEG_INF_F;
#pragma unroll
                for (int kt = 0; kt < 4; ++kt)
#pragma unroll
                    for (int r = 0; r < 4; ++r) mx = fmaxf(mx, sa[qt][kt][r]);
                mx = fmaxf(mx, __shfl_xor(mx, 16));
                mx = fmaxf(mx, __shfl_xor(mx, 32));
                const float mn = fmaxf(m_run[qt], mx);
                const float alpha = __expf(m_run[qt] - mn);
                m_run[qt] = mn;

                float rs = 0.f;
                unsigned int pk[4][2];
#pragma unroll
                for (int kt = 0; kt < 4; ++kt) {
                    float e0 = __expf(sa[qt][kt][0] - mn);
                    float e1 = __expf(sa[qt][kt][1] - mn);
                    float e2 = __expf(sa[qt][kt][2] - mn);
                    float e3 = __expf(sa[qt][kt][3] - mn);
                    rs += (e0 + e1) + (e2 + e3);
                    pk[kt][0] = pkbf(e0, e1);
                    pk[kt][1] = pkbf(e2, e3);
                }
                rs += __shfl_xor(rs, 16);
                rs += __shfl_xor(rs, 32);
                l_run[qt] = l_run[qt] * alpha + rs;

                float ab[4];
#pragma unroll
                for (int r = 0; r < 4; ++r)
                    ab[r] = __shfl(alpha, (lane & 48) + quad * 4 + r);
#pragma unroll
                for (int dt = 0; dt < 4; ++dt)
#pragma unroll
                    for (int r = 0; r < 4; ++r) o[qt][dt][r] *= ab[r];

                pa[qt][0] = __builtin_bit_cast(s16x8, (u32x4){pk[0][0], pk[0][1], pk[1][0], pk[1][1]});
                pa[qt][1] = __builtin_bit_cast(s16x8, (u32x4){pk[2][0], pk[2][1], pk[3][0], pk[3][1]});
            }

            // ---- PV: O += P x V, key order permuted to match pa ----
#pragma unroll
            for (int dt = 0; dt < 4; ++dt) {
                const short* vb = vtbuf + (dt * 16 + l16) * PITCH + quad * 4;
                s16x4 v00 = *reinterpret_cast<const s16x4*>(vb);        // keys 4q..4q+3
                s16x4 v01 = *reinterpret_cast<const s16x4*>(vb + 16);   // keys 16+4q..
                s16x4 v10 = *reinterpret_cast<const s16x4*>(vb + 32);   // keys 32+4q..
                s16x4 v11 = *reinterpret_cast<const s16x4*>(vb + 48);   // keys 48+4q..
                s16x8 vf0 = {v00[0], v00[1], v00[2], v00[3], v01[0], v01[1], v01[2], v01[3]};
                s16x8 vf1 = {v10[0], v10[1], v10[2], v10[3], v11[0], v11[1], v11[2], v11[3]};
#pragma unroll
                for (int qt = 0; qt < 2; ++qt) {
                    o[qt][dt] = __builtin_amdgcn_mfma_f32_16x16x32_bf16(pa[qt][0], vf0, o[qt][dt], 0, 0, 0);
                    o[qt][dt] = __builtin_amdgcn_mfma_f32_16x16x32_bf16(pa[qt][1], vf1, o[qt][dt], 0, 0, 0);
                }
            }
        }
    }

    // ---- epilogue: broadcast l to row layout, normalize, store ----
#pragma unroll
    for (int qt = 0; qt < 2; ++qt) {
#pragma unroll
        for (int r = 0; r < 4; ++r) {
            const float lb = __shfl(l_run[qt], (lane & 48) + quad * 4 + r);
            const float inv = 1.0f / lb;
            const int row = qrow0 + qt * 16 + quad * 4 + r;
            float* op = outg + ((size_t)(b * S_DIM + row) * H_DIM + h) * D_DIM + l16;
#pragma unroll
            for (int dt = 0; dt < 4; ++dt)
                op[dt * 16] = o[qt][dt][r] * inv;
        }
    }
}

extern "C" void kernel_launch(void* const* d_in, const int* in_sizes, int n_in,
                              void* d_out, int out_size, void* d_ws, size_t ws_size,
                              hipStream_t stream) {
    const float* q = (const float*)d_in[0];
    const float* k = (const float*)d_in[1];
    const float* v = (const float*)d_in[2];
    float* out = (float*)d_out;
    const int B = in_sizes[0] / (S_DIM * H_DIM * D_DIM);   // = 2
    dim3 grid(N_BLK / 2, H_DIM, B);
    dim3 block(256);
    hipLaunchKernelGGL(bsattn_kernel, grid, block, 0, stream, q, k, v, out);
}

// Round 4
// 160.559 us; speedup vs baseline: 1.2600x; 1.2600x over previous
//
#include <hip/hip_runtime.h>

#define S_DIM 4096
#define H_DIM 16
#define D_DIM 64
#define N_BLK 64          // S / 64 query blocks
#define NEG_INF_F (-1e30f)
#define QSCALE 0.125f     // 1/sqrt(64), exact

typedef __attribute__((ext_vector_type(4))) float f32x4;
typedef __attribute__((ext_vector_type(8))) short s16x8;
typedef __attribute__((ext_vector_type(4))) unsigned int u32x4;
typedef __attribute__((ext_vector_type(2))) unsigned int u32x2;

__device__ __forceinline__ unsigned int fbits(float f) {
    return __builtin_bit_cast(unsigned int, f);
}
// pack two floats -> two bf16 (round-half-up; inputs never NaN here). lo=a, hi=b
__device__ __forceinline__ unsigned int pkbf(float a, float b) {
    return __builtin_amdgcn_perm(fbits(b) + 0x8000u, fbits(a) + 0x8000u, 0x07060302u);
}

// Block = 4 waves; wave w owns the FULL query block n = n0 + w (64 queries, 4 qt tiles).
// Prologue: all 8 V^T tiles (j = n0-2 .. n0+5) staged to LDS as bf16 pairs, ONE barrier.
// Main loop (5 active stages per wave, NO barriers):
//   K A-fragments loaded directly global->VGPR (coalesced; L3 absorbs re-reads),
//   S^T = K x Q^T -> lane holds S[query=l16][key=kt*16+4*quad+r]; online softmax;
//   lane's exp'ed values form the PV A-fragment directly (k-index permuted, V B-frags
//   read from LDS with the matching permutation).
// V^T LDS layout: row d (0..63), 512 keys as 256 u32 bf16-pairs, column ROTATED by
// 8*d shorts (mod 512) so reads/writes spread across banks (pitch 512 alone would
// collapse to 8 banks).
__global__ __launch_bounds__(256, 2) void bsattn_kernel(
    const float* __restrict__ qg, const float* __restrict__ kg,
    const float* __restrict__ vg, float* __restrict__ outg)
{
    __shared__ unsigned int lds_vt[D_DIM * 256];   // 64 KB: V^T bf16 pairs, rotated

    const int tid  = threadIdx.x;
    const int w    = tid >> 6;
    const int lane = tid & 63;
    const int quad = lane >> 4;
    const int l16  = lane & 15;

    const int b  = blockIdx.z;
    const int h  = blockIdx.y;
    const int n0 = blockIdx.x << 2;
    const int n  = n0 + w;                       // this wave's query block

    // ---- Q fragments (B-operand): bq[qt][hh], pre-scaled, bf16 ----
    s16x8 bq[4][2];
#pragma unroll
    for (int qt = 0; qt < 4; ++qt) {
        const size_t qrow = ((size_t)(b * S_DIM + n * 64 + qt * 16 + l16) * H_DIM + h) * D_DIM;
#pragma unroll
        for (int hh = 0; hh < 2; ++hh) {
            const float4* qp = reinterpret_cast<const float4*>(qg + qrow + hh * 32 + quad * 8);
            float4 f0 = qp[0];
            float4 f1 = qp[1];
            u32x4 u;
            u.x = pkbf(f0.x * QSCALE, f0.y * QSCALE);
            u.y = pkbf(f0.z * QSCALE, f0.w * QSCALE);
            u.z = pkbf(f1.x * QSCALE, f1.y * QSCALE);
            u.w = pkbf(f1.z * QSCALE, f1.w * QSCALE);
            bq[qt][hh] = __builtin_bit_cast(s16x8, u);
        }
    }

    // ---- V^T staging: 8 tiles, once. thread -> (tile jt, row pair 2sp,2sp+1) ----
    {
        const int jt = tid >> 5;                 // 0..7
        const int sp = tid & 31;                 // row-pair index
        const int jv = n0 - 2 + jt;
        if (jv >= 0 && jv < N_BLK) {
            const float* v0p = vg + ((size_t)(b * S_DIM + jv * 64 + 2 * sp) * H_DIM + h) * D_DIM;
            const float* v1p = v0p + H_DIM * D_DIM;
            const int craw = jt * 64 + 2 * sp;   // raw column (key index) of this pair
#pragma unroll
            for (int ch = 0; ch < 4; ++ch) {     // 16 d-values per chunk (bounds transient regs)
                const int d0 = ch * 16;
                const float4* ap = reinterpret_cast<const float4*>(v0p + d0);
                const float4* bp = reinterpret_cast<const float4*>(v1p + d0);
                float4 a0 = ap[0], a1 = ap[1], a2 = ap[2], a3 = ap[3];
                float4 b0 = bp[0], b1 = bp[1], b2 = bp[2], b3 = bp[3];
                float av[16] = {a0.x,a0.y,a0.z,a0.w, a1.x,a1.y,a1.z,a1.w,
                                a2.x,a2.y,a2.z,a2.w, a3.x,a3.y,a3.z,a3.w};
                float bv[16] = {b0.x,b0.y,b0.z,b0.w, b1.x,b1.y,b1.z,b1.w,
                                b2.x,b2.y,b2.z,b2.w, b3.x,b3.y,b3.z,b3.w};
#pragma unroll
                for (int i = 0; i < 16; ++i) {
                    const int d = d0 + i;
                    lds_vt[d * 256 + (((craw + 8 * d) & 511) >> 1)] = pkbf(av[i], bv[i]);
                }
            }
        }
    }

    f32x4 o[4][4];                   // O accum [qt][dt], C layout (row=query, col=d)
    float m_run[4], l_run[4];
#pragma unroll
    for (int qt = 0; qt < 4; ++qt) {
        m_run[qt] = NEG_INF_F; l_run[qt] = 0.f;
#pragma unroll
        for (int dt = 0; dt < 4; ++dt) o[qt][dt] = (f32x4){0.f, 0.f, 0.f, 0.f};
    }

    __syncthreads();                 // V^T visible; no further barriers

    const int colb = quad * 4 + 8 * l16;     // read-column base (rotation part w/o tile/dt)

    for (int t = 0; t < 5; ++t) {
        const int j = n - 2 + t;             // key block (wave-uniform)
        if (j < 0 || j >= N_BLK) continue;
        const int ji = w + t;                // staged tile index = j - n0 + 2

        // ---- K A-fragments direct from global (coalesced 16-row x 128B chunks) ----
        float4 kf[4][2][2];
#pragma unroll
        for (int kt = 0; kt < 4; ++kt) {
            const size_t krow = ((size_t)(b * S_DIM + j * 64 + kt * 16 + l16) * H_DIM + h) * D_DIM + quad * 8;
#pragma unroll
            for (int hh = 0; hh < 2; ++hh) {
                const float4* kp = reinterpret_cast<const float4*>(kg + krow + hh * 32);
                kf[kt][hh][0] = kp[0];
                kf[kt][hh][1] = kp[1];
            }
        }
        s16x8 kbf[4][2];
#pragma unroll
        for (int kt = 0; kt < 4; ++kt)
#pragma unroll
            for (int hh = 0; hh < 2; ++hh) {
                u32x4 u;
                u.x = pkbf(kf[kt][hh][0].x, kf[kt][hh][0].y);
                u.y = pkbf(kf[kt][hh][0].z, kf[kt][hh][0].w);
                u.z = pkbf(kf[kt][hh][1].x, kf[kt][hh][1].y);
                u.w = pkbf(kf[kt][hh][1].z, kf[kt][hh][1].w);
                kbf[kt][hh] = __builtin_bit_cast(s16x8, u);
            }

        // ---- per qt: S^T = K x Q^T, online softmax; P stays in registers ----
        s16x8 pa[4][2];
#pragma unroll
        for (int qt = 0; qt < 4; ++qt) {
            f32x4 sa[4];
#pragma unroll
            for (int kt = 0; kt < 4; ++kt) {
                f32x4 z = {0.f, 0.f, 0.f, 0.f};
                f32x4 a0 = __builtin_amdgcn_mfma_f32_16x16x32_bf16(kbf[kt][0], bq[qt][0], z, 0, 0, 0);
                sa[kt]   = __builtin_amdgcn_mfma_f32_16x16x32_bf16(kbf[kt][1], bq[qt][1], a0, 0, 0, 0);
            }
            float mx = NEG_INF_F;
#pragma unroll
            for (int kt = 0; kt < 4; ++kt)
#pragma unroll
                for (int r = 0; r < 4; ++r) mx = fmaxf(mx, sa[kt][r]);
            mx = fmaxf(mx, __shfl_xor(mx, 16));
            mx = fmaxf(mx, __shfl_xor(mx, 32));
            const float mn = fmaxf(m_run[qt], mx);
            const float alpha = __expf(m_run[qt] - mn);
            m_run[qt] = mn;

            float rs = 0.f;
            unsigned int pk[4][2];
#pragma unroll
            for (int kt = 0; kt < 4; ++kt) {
                float e0 = __expf(sa[kt][0] - mn);
                float e1 = __expf(sa[kt][1] - mn);
                float e2 = __expf(sa[kt][2] - mn);
                float e3 = __expf(sa[kt][3] - mn);
                rs += (e0 + e1) + (e2 + e3);
                pk[kt][0] = pkbf(e0, e1);
                pk[kt][1] = pkbf(e2, e3);
            }
            rs += __shfl_xor(rs, 16);
            rs += __shfl_xor(rs, 32);
            l_run[qt] = l_run[qt] * alpha + rs;

            float ab[4];
#pragma unroll
            for (int r = 0; r < 4; ++r)
                ab[r] = __shfl(alpha, (lane & 48) + quad * 4 + r);
#pragma unroll
            for (int dt = 0; dt < 4; ++dt)
#pragma unroll
                for (int r = 0; r < 4; ++r) o[qt][dt][r] *= ab[r];

            pa[qt][0] = __builtin_bit_cast(s16x8, (u32x4){pk[0][0], pk[0][1], pk[1][0], pk[1][1]});
            pa[qt][1] = __builtin_bit_cast(s16x8, (u32x4){pk[2][0], pk[2][1], pk[3][0], pk[3][1]});
        }

        // ---- PV: O += P x V (B-frags from rotated V^T LDS, permuted key order) ----
        const int cb0 = ji * 64 + colb;
#pragma unroll
        for (int dt = 0; dt < 4; ++dt) {
            const int d = dt * 16 + l16;
            const unsigned int* vrow = lds_vt + d * 256;
            const int cb = cb0 + 128 * dt;
            u32x2 v00 = *reinterpret_cast<const u32x2*>(vrow + (((cb     ) & 511) >> 1));
            u32x2 v01 = *reinterpret_cast<const u32x2*>(vrow + (((cb + 16) & 511) >> 1));
            u32x2 v10 = *reinterpret_cast<const u32x2*>(vrow + (((cb + 32) & 511) >> 1));
            u32x2 v11 = *reinterpret_cast<const u32x2*>(vrow + (((cb + 48) & 511) >> 1));
            s16x8 vf0 = __builtin_bit_cast(s16x8, (u32x4){v00.x, v00.y, v01.x, v01.y});
            s16x8 vf1 = __builtin_bit_cast(s16x8, (u32x4){v10.x, v10.y, v11.x, v11.y});
#pragma unroll
            for (int qt = 0; qt < 4; ++qt) {
                o[qt][dt] = __builtin_amdgcn_mfma_f32_16x16x32_bf16(pa[qt][0], vf0, o[qt][dt], 0, 0, 0);
                o[qt][dt] = __builtin_amdgcn_mfma_f32_16x16x32_bf16(pa[qt][1], vf1, o[qt][dt], 0, 0, 0);
            }
        }
    }

    // ---- epilogue: broadcast l to row layout, normalize, store ----
#pragma unroll
    for (int qt = 0; qt < 4; ++qt) {
#pragma unroll
        for (int r = 0; r < 4; ++r) {
            const float lb = __shfl(l_run[qt], (lane & 48) + quad * 4 + r);
            const float inv = 1.0f / lb;
            const int row = n * 64 + qt * 16 + quad * 4 + r;
            float* op = outg + ((size_t)(b * S_DIM + row) * H_DIM + h) * D_DIM + l16;
#pragma unroll
            for (int dt = 0; dt < 4; ++dt)
                op[dt * 16] = o[qt][dt][r] * inv;
        }
    }
}

extern "C" void kernel_launch(void* const* d_in, const int* in_sizes, int n_in,
                              void* d_out, int out_size, void* d_ws, size_t ws_size,
                              hipStream_t stream) {
    const float* q = (const float*)d_in[0];
    const float* k = (const float*)d_in[1];
    const float* v = (const float*)d_in[2];
    float* out = (float*)d_out;
    const int B = in_sizes[0] / (S_DIM * H_DIM * D_DIM);   // = 2
    dim3 grid(N_BLK / 4, H_DIM, B);
    dim3 block(256);
    hipLaunchKernelGGL(bsattn_kernel, grid, block, 0, stream, q, k, v, out);
}